// Round 2
// baseline (318.839 us; speedup 1.0000x reference)
//
#include <hip/hip_runtime.h>
#include <cstdint>
#include <cstddef>

// SLAYER SRM-alpha constants, rounded-to-nearest f32 from double
#define THETA_F 10.0f
#define DS_C 0.9048374180359595731642491f   // exp(-0.1)
#define DR_C 0.3678794411714423215955238f   // exp(-1.0)
#define CS_C 0.2718281828459045235360287f   // e/10
#define CR_C -54.3656365691809047072057f    // -2*10*e

// ---------------------------------------------------------------------------
// K1: layer-1 fc (K=4, binary inputs) + psp_spike recursion.
// One thread per (b,h) channel; 2000 serial steps; spikes bit-packed via ballot.
// All per-step operands live in registers: input codes staged once in LDS and
// consumed as u64 (8 codes) per 8 steps with manual prefetch; a_t built from
// w0..w3 via cndmask selects (bit-identical to mul-by-{0,1} + ordered adds).
// grid 128 (b = blk>>1, h0 = (blk&1)*256), block 256.
// s1p layout: u64 [64][2000][8]   (bit l of word g = spike of h = g*64+l)
// ---------------------------------------------------------------------------
__global__ __launch_bounds__(256) void k1_layer1(
    const float* __restrict__ inp,                 // [64][4][2000]
    const float* __restrict__ W1,                  // [512][4]
    unsigned long long* __restrict__ s1p)          // [64][2000][8]
{
    __shared__ alignas(8) unsigned char codes[2048];

    const int tid = threadIdx.x;
    const int b  = blockIdx.x >> 1;
    const int h0 = (blockIdx.x & 1) << 8;
    const int h  = h0 + tid;

    const float w0 = W1[h * 4 + 0];
    const float w1 = W1[h * 4 + 1];
    const float w2 = W1[h * 4 + 2];
    const float w3 = W1[h * 4 + 3];

    // stage all 2000 input codes (4-bit per t), one-time
    for (int t = tid; t < 2000; t += 256) {
        const float v0 = inp[(b * 4 + 0) * 2000 + t];
        const float v1 = inp[(b * 4 + 1) * 2000 + t];
        const float v2 = inp[(b * 4 + 2) * 2000 + t];
        const float v3 = inp[(b * 4 + 3) * 2000 + t];
        codes[t] = (unsigned char)((int)(v0 != 0.0f) | ((int)(v1 != 0.0f) << 1) |
                                   ((int)(v2 != 0.0f) << 2) | ((int)(v3 != 0.0f) << 3));
    }
    __syncthreads();

    float xs = 0.0f, ys = 0.0f, xr = 0.0f, yr = 0.0f;
    const int  g      = (h0 >> 6) + (tid >> 6);
    const bool w_lead = (tid & 63) == 0;
    unsigned long long* outp = s1p + (size_t)b * 16000 + g;

    unsigned long long cw = *reinterpret_cast<const unsigned long long*>(codes);
    for (int t0 = 0; t0 < 2000; t0 += 8) {
        const unsigned long long cwn = (t0 + 8 < 2000)
            ? *reinterpret_cast<const unsigned long long*>(codes + t0 + 8) : 0ull;
        #pragma unroll
        for (int j = 0; j < 8; ++j) {
            const int c = (int)(cw >> (8 * j)) & 15;
            // a = ((w0*b0 + w1*b1) + w2*b2) + w3*b3; selects == mul-by-{0,1}
            const float a = __fadd_rn(__fadd_rn(__fadd_rn(
                                (c & 1) ? w0 : 0.0f,
                                (c & 2) ? w1 : 0.0f),
                                (c & 4) ? w2 : 0.0f),
                                (c & 8) ? w3 : 0.0f);
            // membrane from carry state; (u>=theta) == ((u-theta)>=0) in IEEE
            const float u  = __fadd_rn(__fmul_rn(CS_C, ys), __fmul_rn(CR_C, yr));
            const bool  sp = (u >= THETA_F);
            // state updates, exact reference rounding (TS=1 mults elided)
            xs = __fadd_rn(__fmul_rn(DS_C, xs), a);
            ys = __fmul_rn(DS_C, __fadd_rn(ys, xs));
            const float A = __fmul_rn(DR_C, xr);       // dr*xr + s, s in {0,1}
            xr = sp ? __fadd_rn(A, 1.0f) : A;
            yr = __fmul_rn(DR_C, __fadd_rn(yr, xr));

            const unsigned long long m = __ballot(sp);
            if (w_lead) outp[(size_t)(t0 + j) * 8] = m;
        }
        cw = cwn;
    }
}

// ---------------------------------------------------------------------------
// K2: a2[b,o,t] = sum_h W2[o,h] * s1[b,h,t]  (ascending h; zero terms skipped
// -- bitwise identical since adding +0.0 is a no-op and accs start at +0).
// One thread per (b,t). Writes a2 rows [b*2+o][2000] into d_out (staging).
// ---------------------------------------------------------------------------
__global__ __launch_bounds__(256) void k2_fc2(
    const unsigned long long* __restrict__ s1p,    // [64][2000][8]
    const float* __restrict__ W2,                  // [2][512]
    float* __restrict__ a2)                        // [128][2000]
{
    __shared__ float w2s[1024];
    const int tid = threadIdx.x;
    for (int j = tid; j < 1024; j += 256) w2s[j] = W2[j];
    __syncthreads();

    const int idx = blockIdx.x * 256 + tid;        // = b*2000 + t, 0..127999
    const unsigned long long* mp = s1p + (size_t)idx * 8;

    float acc0 = 0.0f, acc1 = 0.0f;
    #pragma unroll
    for (int gg = 0; gg < 8; ++gg) {
        unsigned long long m = mp[gg];
        while (m) {
            const int i = __builtin_ctzll(m);
            m &= m - 1;
            const int hh = gg * 64 + i;
            acc0 = __fadd_rn(acc0, w2s[hh]);
            acc1 = __fadd_rn(acc1, w2s[512 + hh]);
        }
    }
    const int b = idx / 2000;
    const int t = idx - b * 2000;
    a2[(size_t)(b * 2 + 0) * 2000 + t] = acc0;
    a2[(size_t)(b * 2 + 1) * 2000 + t] = acc1;
}

// ---------------------------------------------------------------------------
// K3: layer-2 psp_spike + final psp readout, fused. 128 chains (b,o).
// Reads a2 in-place from d_out rows and overwrites with p. 4-deep float4
// prefetch ring hides L2/HBM latency (loads issued 16 steps ahead).
// grid 2 x block 64.
// ---------------------------------------------------------------------------
__global__ __launch_bounds__(64) void k3_layer2(float* __restrict__ io)
{
    const int idx = blockIdx.x * 64 + threadIdx.x; // row = b*2+o, 0..127
    float* row = io + (size_t)idx * 2000;

    float xs2 = 0.0f, ys2 = 0.0f, xr2 = 0.0f, yr2 = 0.0f;
    float xs3 = 0.0f, ys3 = 0.0f;

    float4 b0 = *reinterpret_cast<const float4*>(row + 0);
    float4 b1 = *reinterpret_cast<const float4*>(row + 4);
    float4 b2 = *reinterpret_cast<const float4*>(row + 8);
    float4 b3 = *reinterpret_cast<const float4*>(row + 12);

    for (int t = 0; t < 2000; t += 4) {
        const float4 cur = b0;
        b0 = b1; b1 = b2; b2 = b3;
        if (t + 16 < 2000) b3 = *reinterpret_cast<const float4*>(row + t + 16);

        const float av[4] = {cur.x, cur.y, cur.z, cur.w};
        float p[4];
        #pragma unroll
        for (int j = 0; j < 4; ++j) {
            const float u  = __fadd_rn(__fmul_rn(CS_C, ys2), __fmul_rn(CR_C, yr2));
            const bool  sp = (u >= THETA_F);
            p[j] = __fmul_rn(CS_C, ys3);               // readout BEFORE consuming s2[t]
            // layer-2 neuron state
            xs2 = __fadd_rn(__fmul_rn(DS_C, xs2), av[j]);
            ys2 = __fmul_rn(DS_C, __fadd_rn(ys2, xs2));
            const float A = __fmul_rn(DR_C, xr2);
            xr2 = sp ? __fadd_rn(A, 1.0f) : A;
            yr2 = __fmul_rn(DR_C, __fadd_rn(yr2, xr2));
            // readout psp state driven by s2
            const float s = sp ? 1.0f : 0.0f;
            xs3 = __fadd_rn(__fmul_rn(DS_C, xs3), s);
            ys3 = __fmul_rn(DS_C, __fadd_rn(ys3, xs3));
        }
        *reinterpret_cast<float4*>(row + t) = make_float4(p[0], p[1], p[2], p[3]);
    }
}

extern "C" void kernel_launch(void* const* d_in, const int* in_sizes, int n_in,
                              void* d_out, int out_size, void* d_ws, size_t ws_size,
                              hipStream_t stream)
{
    const float* inp = (const float*)d_in[0];  // [64][4][2000]
    const float* W1  = (const float*)d_in[1];  // [512][4]
    const float* W2  = (const float*)d_in[2];  // [2][512]
    float* out = (float*)d_out;                // [64][2][2000]

    unsigned long long* s1p = (unsigned long long*)d_ws;   // 8,192,000 B

    k1_layer1<<<dim3(128), dim3(256), 0, stream>>>(inp, W1, s1p);
    k2_fc2<<<dim3(500), dim3(256), 0, stream>>>(s1p, W2, out);
    k3_layer2<<<dim3(2), dim3(64), 0, stream>>>(out);
}

// Round 3
// 239.575 us; speedup vs baseline: 1.3309x; 1.3309x over previous
//
#include <hip/hip_runtime.h>
#include <cstdint>
#include <cstddef>

// SLAYER SRM-alpha constants, rounded-to-nearest f32 from double
#define THETA_F 10.0f
#define DS_C 0.9048374180359595731642491f   // exp(-0.1)
#define DR_C 0.3678794411714423215955238f   // exp(-1.0)
#define CS_C 0.2718281828459045235360287f   // e/10
#define CR_C -54.3656365691809047072057f    // -2*10*e

typedef unsigned int       u32;
typedef unsigned long long u64;
typedef unsigned short     u16;

// ws layout (exactly 8,192,000 bytes = 64*512*2000 bits):
//   w32 region : u32 [64][62][512]  bits for t in [tb*32, tb*32+32), bit j = t%32
//   tail region: u16 [64][512] at byte offset 64*62*512*4 = 8,126,464, bits t in [1984,2000)
#define W32_WORDS_PER_B  (62 * 512)
#define TAIL_BYTE_OFF    (64 * 62 * 512 * 4)

// ---------------------------------------------------------------------------
// K1: layer-1 fc (K=4, binary inputs -> 16-entry LDS table) + psp_spike.
// One thread per (b,h); 2000 serial steps. Issue-lean inner loop:
//  - a_t: single ds_read from table, double-buffered 8-ahead (latency hidden)
//  - spike bit: or+cndmask into per-lane u32, coalesced store every 32 steps
// grid 128 (b = blk>>1, h0 = (blk&1)*256), block 256.
// ---------------------------------------------------------------------------
__global__ __launch_bounds__(256) void k1_layer1(
    const float* __restrict__ inp,                 // [64][4][2000]
    const float* __restrict__ W1,                  // [512][4]
    u32* __restrict__ w32, u16* __restrict__ tail16)
{
    __shared__ float table[16 * 256];
    __shared__ alignas(8) unsigned char codes[2048];

    const int tid = threadIdx.x;
    const int b  = blockIdx.x >> 1;
    const int h0 = (blockIdx.x & 1) << 8;
    const int h  = h0 + tid;

    const float w0 = W1[h * 4 + 0];
    const float w1 = W1[h * 4 + 1];
    const float w2 = W1[h * 4 + 2];
    const float w3 = W1[h * 4 + 3];
    // table[c] = ((w0*b0 + w1*b1) + w2*b2) + w3*b3, b_i in {0,1}: bit-identical
    // to the reference einsum contraction (passed R0/R1 with this form).
    for (int c = 0; c < 16; ++c) {
        float v = __fmul_rn(w0, (c & 1) ? 1.0f : 0.0f);
        v = __fadd_rn(v, __fmul_rn(w1, (c & 2) ? 1.0f : 0.0f));
        v = __fadd_rn(v, __fmul_rn(w2, (c & 4) ? 1.0f : 0.0f));
        v = __fadd_rn(v, __fmul_rn(w3, (c & 8) ? 1.0f : 0.0f));
        table[c * 256 + tid] = v;
    }
    // stage all 2000 input codes (4-bit per t)
    for (int t = tid; t < 2000; t += 256) {
        const float v0 = inp[(b * 4 + 0) * 2000 + t];
        const float v1 = inp[(b * 4 + 1) * 2000 + t];
        const float v2 = inp[(b * 4 + 2) * 2000 + t];
        const float v3 = inp[(b * 4 + 3) * 2000 + t];
        codes[t] = (unsigned char)((int)(v0 != 0.0f) | ((int)(v1 != 0.0f) << 1) |
                                   ((int)(v2 != 0.0f) << 2) | ((int)(v3 != 0.0f) << 3));
    }
    if (tid < 48) codes[2000 + tid] = 0;   // pad (reads masked anyway)
    __syncthreads();

#define ISSUE(CW, BUF) do {                                                   \
        const u32 lo_ = (u32)(CW), hi_ = (u32)((CW) >> 32);                   \
        BUF[0] = table[((lo_      ) & 15) * 256 + tid];                       \
        BUF[1] = table[((lo_ >>  8) & 15) * 256 + tid];                       \
        BUF[2] = table[((lo_ >> 16) & 15) * 256 + tid];                       \
        BUF[3] = table[((lo_ >> 24) & 15) * 256 + tid];                       \
        BUF[4] = table[((hi_      ) & 15) * 256 + tid];                       \
        BUF[5] = table[((hi_ >>  8) & 15) * 256 + tid];                       \
        BUF[6] = table[((hi_ >> 16) & 15) * 256 + tid];                       \
        BUF[7] = table[((hi_ >> 24) & 15) * 256 + tid];                       \
    } while (0)

    // exact reference rounding (TS=1 mults elided; (u>=theta) == ((u-theta)>=0))
#define STEP(AV, BITPOS) do {                                                 \
        const float u_ = __fadd_rn(__fmul_rn(CS_C, ys), __fmul_rn(CR_C, yr)); \
        const bool sp_ = (u_ >= THETA_F);                                     \
        xs = __fadd_rn(__fmul_rn(DS_C, xs), (AV));                            \
        ys = __fmul_rn(DS_C, __fadd_rn(ys, xs));                              \
        const float A_ = __fmul_rn(DR_C, xr);                                 \
        xr = sp_ ? __fadd_rn(A_, 1.0f) : A_;                                  \
        yr = __fmul_rn(DR_C, __fadd_rn(yr, xr));                              \
        bits = sp_ ? (bits | (1u << (BITPOS))) : bits;                        \
    } while (0)

#define STEP8(BUF, J0) do {                                                   \
        _Pragma("unroll")                                                     \
        for (int j_ = 0; j_ < 8; ++j_) STEP(BUF[j_], (J0) + j_);              \
    } while (0)

    float xs = 0.0f, ys = 0.0f, xr = 0.0f, yr = 0.0f;
    u32 bits = 0;
    u32* pw = w32 + (size_t)b * W32_WORDS_PER_B + h;

    float bA[8], bB[8];
    u64 cw = *reinterpret_cast<const u64*>(codes);
    ISSUE(cw, bA);
    u64 c1 = *reinterpret_cast<const u64*>(codes + 8);
    u64 c2 = *reinterpret_cast<const u64*>(codes + 16);
    u64 c3 = *reinterpret_cast<const u64*>(codes + 24);
    u64 c4 = *reinterpret_cast<const u64*>(codes + 32);

    for (int t0 = 0; t0 < 1984; t0 += 32) {
        ISSUE(c1, bB);
        const u64 n1 = *reinterpret_cast<const u64*>(codes + t0 + 40);
        const u64 n2 = *reinterpret_cast<const u64*>(codes + t0 + 48);
        const u64 n3 = *reinterpret_cast<const u64*>(codes + t0 + 56);
        const u64 n4 = *reinterpret_cast<const u64*>(codes + t0 + 64);
        STEP8(bA, 0);
        ISSUE(c2, bA);
        STEP8(bB, 8);
        ISSUE(c3, bB);
        STEP8(bA, 16);
        ISSUE(c4, bA);
        STEP8(bB, 24);
        *pw = bits; pw += 512; bits = 0;
        c1 = n1; c2 = n2; c3 = n3; c4 = n4;
    }
    // tail: bA holds t=1984..1991 (issued with c4 at t0=1952); c1 = codes[1992..2000)
    ISSUE(c1, bB);
    STEP8(bA, 0);
    STEP8(bB, 8);
    tail16[b * 512 + h] = (u16)bits;

#undef STEP8
#undef STEP
#undef ISSUE
}

// ---------------------------------------------------------------------------
// K2: a2[b,o,t] = ascending-h sum of W2[o,h]*s1[b,h,t]; cndmask +0.0 adds are
// bit-identical to the reference skip-zero ascending sum (+0 is additive id;
// acc never becomes -0 since x+(-x)=+0 under RN).
// Block per (b, it): stages 8 tb-words x 512 h in LDS, thread per t.
// ---------------------------------------------------------------------------
__global__ __launch_bounds__(256) void k2_fc2(
    const u32* __restrict__ w32, const u16* __restrict__ tail16,
    const float* __restrict__ W2,                  // [2][512]
    float* __restrict__ a2)                        // [128][2000]
{
    __shared__ float w2s[1024];
    __shared__ u32 stage[4096];                    // [local tb 0..7][h 0..511]

    const int tid = threadIdx.x;
    const int b  = blockIdx.x >> 3;
    const int it = blockIdx.x & 7;

    for (int j = tid; j < 1024; j += 256) w2s[j] = W2[j];
    #pragma unroll
    for (int k = 0; k < 16; ++k) {
        const int l = tid + (k << 8);              // 0..4095
        const int gtb = (it << 3) + (l >> 9);
        u32 v = 0;
        if (gtb < 62)       v = w32[((size_t)b * 62 + gtb) * 512 + (l & 511)];
        else if (gtb == 62) v = (u32)tail16[b * 512 + (l & 511)];
        stage[l] = v;
    }
    __syncthreads();

    const int t = (it << 8) + tid;
    if (t < 2000) {
        const u32* srow = stage + ((tid >> 5) << 9);
        const int sh = tid & 31;
        float acc0 = 0.0f, acc1 = 0.0f;
        #pragma unroll 8
        for (int hh = 0; hh < 512; ++hh) {
            const bool on = (srow[hh] >> sh) & 1u;
            acc0 = __fadd_rn(acc0, on ? w2s[hh] : 0.0f);
            acc1 = __fadd_rn(acc1, on ? w2s[512 + hh] : 0.0f);
        }
        a2[(size_t)(b * 2 + 0) * 2000 + t] = acc0;
        a2[(size_t)(b * 2 + 1) * 2000 + t] = acc1;
    }
}

// ---------------------------------------------------------------------------
// K3: layer-2 psp_spike + final psp readout, fused (unchanged, passed R1/R2).
// ---------------------------------------------------------------------------
__global__ __launch_bounds__(64) void k3_layer2(float* __restrict__ io)
{
    const int idx = blockIdx.x * 64 + threadIdx.x; // row = b*2+o, 0..127
    float* row = io + (size_t)idx * 2000;

    float xs2 = 0.0f, ys2 = 0.0f, xr2 = 0.0f, yr2 = 0.0f;
    float xs3 = 0.0f, ys3 = 0.0f;

    float4 b0 = *reinterpret_cast<const float4*>(row + 0);
    float4 b1 = *reinterpret_cast<const float4*>(row + 4);
    float4 b2 = *reinterpret_cast<const float4*>(row + 8);
    float4 b3 = *reinterpret_cast<const float4*>(row + 12);

    for (int t = 0; t < 2000; t += 4) {
        const float4 cur = b0;
        b0 = b1; b1 = b2; b2 = b3;
        if (t + 16 < 2000) b3 = *reinterpret_cast<const float4*>(row + t + 16);

        const float av[4] = {cur.x, cur.y, cur.z, cur.w};
        float p[4];
        #pragma unroll
        for (int j = 0; j < 4; ++j) {
            const float u  = __fadd_rn(__fmul_rn(CS_C, ys2), __fmul_rn(CR_C, yr2));
            const bool  sp = (u >= THETA_F);
            p[j] = __fmul_rn(CS_C, ys3);               // readout BEFORE consuming s2[t]
            xs2 = __fadd_rn(__fmul_rn(DS_C, xs2), av[j]);
            ys2 = __fmul_rn(DS_C, __fadd_rn(ys2, xs2));
            const float A = __fmul_rn(DR_C, xr2);
            xr2 = sp ? __fadd_rn(A, 1.0f) : A;
            yr2 = __fmul_rn(DR_C, __fadd_rn(yr2, xr2));
            const float s = sp ? 1.0f : 0.0f;
            xs3 = __fadd_rn(__fmul_rn(DS_C, xs3), s);
            ys3 = __fmul_rn(DS_C, __fadd_rn(ys3, xs3));
        }
        *reinterpret_cast<float4*>(row + t) = make_float4(p[0], p[1], p[2], p[3]);
    }
}

extern "C" void kernel_launch(void* const* d_in, const int* in_sizes, int n_in,
                              void* d_out, int out_size, void* d_ws, size_t ws_size,
                              hipStream_t stream)
{
    const float* inp = (const float*)d_in[0];  // [64][4][2000]
    const float* W1  = (const float*)d_in[1];  // [512][4]
    const float* W2  = (const float*)d_in[2];  // [2][512]
    float* out = (float*)d_out;                // [64][2][2000]

    u32* w32    = (u32*)d_ws;
    u16* tail16 = (u16*)((char*)d_ws + TAIL_BYTE_OFF);

    k1_layer1<<<dim3(128), dim3(256), 0, stream>>>(inp, W1, w32, tail16);
    k2_fc2<<<dim3(512), dim3(256), 0, stream>>>(w32, tail16, W2, out);
    k3_layer2<<<dim3(2), dim3(64), 0, stream>>>(out);
}

// Round 4
// 214.303 us; speedup vs baseline: 1.4878x; 1.1179x over previous
//
#include <hip/hip_runtime.h>
#include <cstdint>
#include <cstddef>

// SLAYER SRM-alpha constants, rounded-to-nearest f32 from double
#define THETA_F 10.0f
#define DS_C 0.9048374180359595731642491f   // exp(-0.1)
#define DR_C 0.3678794411714423215955238f   // exp(-1.0)
#define CS_C 0.2718281828459045235360287f   // e/10
#define CR_C -54.3656365691809047072057f    // -2*10*e

typedef unsigned int       u32;
typedef unsigned long long u64;
typedef unsigned short     u16;

// ws layout (exactly 8,192,000 bytes = 64*512*2000 bits):
//   w32 region : u32 [64][62][512]  bits for t in [tb*32, tb*32+32), bit j = t%32
//   tail region: u16 [64][512] at byte offset 64*62*512*4 = 8,126,464, bits t in [1984,2000)
#define W32_WORDS_PER_B  (62 * 512)
#define TAIL_BYTE_OFF    (64 * 62 * 512 * 4)

// ---------------------------------------------------------------------------
// K1: layer-1 fc (K=4, binary inputs -> 16-entry LDS table) + psp_spike.
// One thread per (b,h); 2000 serial steps. 64 blocks x 512 threads (one b per
// block) -> 8 waves/CU = 2 waves/SIMD so dependency stalls of one wave are
// filled by the other's issue. Per step: 1 prefetched ds_read (8-ahead,
// double-buffered) + ~15 VALU; spike bits accumulate into a u32, one coalesced
// store per 32 steps.
// ---------------------------------------------------------------------------
__global__ __launch_bounds__(512) void k1_layer1(
    const float* __restrict__ inp,                 // [64][4][2000]
    const float* __restrict__ W1,                  // [512][4]
    u32* __restrict__ w32, u16* __restrict__ tail16)
{
    __shared__ float table[16 * 512];
    __shared__ alignas(8) unsigned char codes[2048];

    const int tid = threadIdx.x;                   // = h, 0..511
    const int b   = blockIdx.x;                    // 0..63

    const float w0 = W1[tid * 4 + 0];
    const float w1 = W1[tid * 4 + 1];
    const float w2 = W1[tid * 4 + 2];
    const float w3 = W1[tid * 4 + 3];
    // table[c] = ((w0*b0 + w1*b1) + w2*b2) + w3*b3, b_i in {0,1}: bit-identical
    // to the reference einsum contraction (established passing form).
    for (int c = 0; c < 16; ++c) {
        float v = __fmul_rn(w0, (c & 1) ? 1.0f : 0.0f);
        v = __fadd_rn(v, __fmul_rn(w1, (c & 2) ? 1.0f : 0.0f));
        v = __fadd_rn(v, __fmul_rn(w2, (c & 4) ? 1.0f : 0.0f));
        v = __fadd_rn(v, __fmul_rn(w3, (c & 8) ? 1.0f : 0.0f));
        table[c * 512 + tid] = v;
    }
    // stage all 2000 input codes (4-bit per t)
    for (int t = tid; t < 2000; t += 512) {
        const float v0 = inp[(b * 4 + 0) * 2000 + t];
        const float v1 = inp[(b * 4 + 1) * 2000 + t];
        const float v2 = inp[(b * 4 + 2) * 2000 + t];
        const float v3 = inp[(b * 4 + 3) * 2000 + t];
        codes[t] = (unsigned char)((int)(v0 != 0.0f) | ((int)(v1 != 0.0f) << 1) |
                                   ((int)(v2 != 0.0f) << 2) | ((int)(v3 != 0.0f) << 3));
    }
    if (tid < 48) codes[2000 + tid] = 0;   // pad
    __syncthreads();

#define ISSUE(CW, BUF) do {                                                   \
        const u32 lo_ = (u32)(CW), hi_ = (u32)((CW) >> 32);                   \
        BUF[0] = table[((lo_      ) & 15) * 512 + tid];                       \
        BUF[1] = table[((lo_ >>  8) & 15) * 512 + tid];                       \
        BUF[2] = table[((lo_ >> 16) & 15) * 512 + tid];                       \
        BUF[3] = table[((lo_ >> 24) & 15) * 512 + tid];                       \
        BUF[4] = table[((hi_      ) & 15) * 512 + tid];                       \
        BUF[5] = table[((hi_ >>  8) & 15) * 512 + tid];                       \
        BUF[6] = table[((hi_ >> 16) & 15) * 512 + tid];                       \
        BUF[7] = table[((hi_ >> 24) & 15) * 512 + tid];                       \
    } while (0)

    // exact reference rounding (TS=1 mults elided; (u>=theta) == ((u-theta)>=0);
    // xr >= 0 always so cndmask(A+1, A) == A + s bitwise)
#define STEP(AV, BITPOS) do {                                                 \
        const float u_ = __fadd_rn(__fmul_rn(CS_C, ys), __fmul_rn(CR_C, yr)); \
        const bool sp_ = (u_ >= THETA_F);                                     \
        xs = __fadd_rn(__fmul_rn(DS_C, xs), (AV));                            \
        ys = __fmul_rn(DS_C, __fadd_rn(ys, xs));                              \
        const float A_ = __fmul_rn(DR_C, xr);                                 \
        xr = sp_ ? __fadd_rn(A_, 1.0f) : A_;                                  \
        yr = __fmul_rn(DR_C, __fadd_rn(yr, xr));                              \
        bits = sp_ ? (bits | (1u << (BITPOS))) : bits;                        \
    } while (0)

#define STEP8(BUF, J0) do {                                                   \
        _Pragma("unroll")                                                     \
        for (int j_ = 0; j_ < 8; ++j_) STEP(BUF[j_], (J0) + j_);              \
    } while (0)

    float xs = 0.0f, ys = 0.0f, xr = 0.0f, yr = 0.0f;
    u32 bits = 0;
    u32* pw = w32 + (size_t)b * W32_WORDS_PER_B + tid;

    float bA[8], bB[8];
    u64 cw = *reinterpret_cast<const u64*>(codes);
    ISSUE(cw, bA);
    u64 c1 = *reinterpret_cast<const u64*>(codes + 8);
    u64 c2 = *reinterpret_cast<const u64*>(codes + 16);
    u64 c3 = *reinterpret_cast<const u64*>(codes + 24);
    u64 c4 = *reinterpret_cast<const u64*>(codes + 32);

    for (int t0 = 0; t0 < 1984; t0 += 32) {
        ISSUE(c1, bB);
        const u64 n1 = *reinterpret_cast<const u64*>(codes + t0 + 40);
        const u64 n2 = *reinterpret_cast<const u64*>(codes + t0 + 48);
        const u64 n3 = *reinterpret_cast<const u64*>(codes + t0 + 56);
        const u64 n4 = *reinterpret_cast<const u64*>(codes + t0 + 64);
        STEP8(bA, 0);
        ISSUE(c2, bA);
        STEP8(bB, 8);
        ISSUE(c3, bB);
        STEP8(bA, 16);
        ISSUE(c4, bA);
        STEP8(bB, 24);
        *pw = bits; pw += 512; bits = 0;
        c1 = n1; c2 = n2; c3 = n3; c4 = n4;
    }
    // tail: bA holds t=1984..1991 (issued with c4 at t0=1952); c1 = codes[1992..2000)
    ISSUE(c1, bB);
    STEP8(bA, 0);
    STEP8(bB, 8);
    tail16[b * 512 + tid] = (u16)bits;

#undef STEP8
#undef STEP
#undef ISSUE
}

// ---------------------------------------------------------------------------
// K2: a2[b,o,t] = ascending-h sum of W2[o,h]*s1[b,h,t]; cndmask +0.0 adds are
// bit-identical to the reference skip-zero ascending sum.
// Block per (b, it): stages 8 tb-words x 512 h in LDS, thread per t.
// ---------------------------------------------------------------------------
__global__ __launch_bounds__(256) void k2_fc2(
    const u32* __restrict__ w32, const u16* __restrict__ tail16,
    const float* __restrict__ W2,                  // [2][512]
    float* __restrict__ a2)                        // [128][2000]
{
    __shared__ float w2s[1024];
    __shared__ u32 stage[4096];                    // [local tb 0..7][h 0..511]

    const int tid = threadIdx.x;
    const int b  = blockIdx.x >> 3;
    const int it = blockIdx.x & 7;

    for (int j = tid; j < 1024; j += 256) w2s[j] = W2[j];
    #pragma unroll
    for (int k = 0; k < 16; ++k) {
        const int l = tid + (k << 8);              // 0..4095
        const int gtb = (it << 3) + (l >> 9);
        u32 v = 0;
        if (gtb < 62)       v = w32[((size_t)b * 62 + gtb) * 512 + (l & 511)];
        else if (gtb == 62) v = (u32)tail16[b * 512 + (l & 511)];
        stage[l] = v;
    }
    __syncthreads();

    const int t = (it << 8) + tid;
    if (t < 2000) {
        const u32* srow = stage + ((tid >> 5) << 9);
        const int sh = tid & 31;
        float acc0 = 0.0f, acc1 = 0.0f;
        #pragma unroll 8
        for (int hh = 0; hh < 512; ++hh) {
            const bool on = (srow[hh] >> sh) & 1u;
            acc0 = __fadd_rn(acc0, on ? w2s[hh] : 0.0f);
            acc1 = __fadd_rn(acc1, on ? w2s[512 + hh] : 0.0f);
        }
        a2[(size_t)(b * 2 + 0) * 2000 + t] = acc0;
        a2[(size_t)(b * 2 + 1) * 2000 + t] = acc1;
    }
}

// ---------------------------------------------------------------------------
// K3: layer-2 psp_spike + final psp readout, fused. 128 chains (b,o), in-place
// on d_out rows. Full 32-step unroll, 8 named float4 buffers: each quad
// consumes its buffer, stores p, reloads the buffer from t+32 (clamped at the
// tail so no OOB). 8 loads in flight, issued ~28 steps (>1000 cy) before use;
// no ring-shift movs. grid 2 x block 64.
// ---------------------------------------------------------------------------
__global__ __launch_bounds__(64) void k3_layer2(float* __restrict__ io)
{
    const int idx = blockIdx.x * 64 + threadIdx.x; // row = b*2+o, 0..127
    float* row = io + (size_t)idx * 2000;

    float xs2 = 0.0f, ys2 = 0.0f, xr2 = 0.0f, yr2 = 0.0f;
    float xs3 = 0.0f, ys3 = 0.0f;

    // exact reference rounding; xs3,xr2 >= 0 so cndmask(B+1,B) == B+s bitwise
#define K3STEP(AV, POUT) do {                                                 \
        const float u_ = __fadd_rn(__fmul_rn(CS_C, ys2), __fmul_rn(CR_C, yr2)); \
        const bool sp_ = (u_ >= THETA_F);                                     \
        POUT = __fmul_rn(CS_C, ys3);      /* readout BEFORE consuming s2[t] */\
        xs2 = __fadd_rn(__fmul_rn(DS_C, xs2), (AV));                          \
        ys2 = __fmul_rn(DS_C, __fadd_rn(ys2, xs2));                           \
        const float A_ = __fmul_rn(DR_C, xr2);                                \
        xr2 = sp_ ? __fadd_rn(A_, 1.0f) : A_;                                 \
        yr2 = __fmul_rn(DR_C, __fadd_rn(yr2, xr2));                           \
        const float B_ = __fmul_rn(DS_C, xs3);                                \
        xs3 = sp_ ? __fadd_rn(B_, 1.0f) : B_;                                 \
        ys3 = __fmul_rn(DS_C, __fadd_rn(ys3, xs3));                           \
    } while (0)

    // consume BK (4 steps at t0+OFF), store p-quad, reload BK from t0+32+OFF
#define QUAD(BK, OFF) do {                                                    \
        float p0_, p1_, p2_, p3_;                                             \
        K3STEP(BK.x, p0_); K3STEP(BK.y, p1_);                                 \
        K3STEP(BK.z, p2_); K3STEP(BK.w, p3_);                                 \
        *reinterpret_cast<float4*>(row + t0 + (OFF)) =                        \
            make_float4(p0_, p1_, p2_, p3_);                                  \
        const int tn_ = t0 + 32 + (OFF);                                      \
        BK = *reinterpret_cast<const float4*>(row + ((tn_ < 2000) ? tn_ : 1984)); \
    } while (0)

#define TAILQUAD(BK, TPOS) do {                                               \
        float p0_, p1_, p2_, p3_;                                             \
        K3STEP(BK.x, p0_); K3STEP(BK.y, p1_);                                 \
        K3STEP(BK.z, p2_); K3STEP(BK.w, p3_);                                 \
        *reinterpret_cast<float4*>(row + (TPOS)) =                            \
            make_float4(p0_, p1_, p2_, p3_);                                  \
    } while (0)

    float4 b0 = *reinterpret_cast<const float4*>(row + 0);
    float4 b1 = *reinterpret_cast<const float4*>(row + 4);
    float4 b2 = *reinterpret_cast<const float4*>(row + 8);
    float4 b3 = *reinterpret_cast<const float4*>(row + 12);
    float4 b4 = *reinterpret_cast<const float4*>(row + 16);
    float4 b5 = *reinterpret_cast<const float4*>(row + 20);
    float4 b6 = *reinterpret_cast<const float4*>(row + 24);
    float4 b7 = *reinterpret_cast<const float4*>(row + 28);

    for (int t0 = 0; t0 < 1984; t0 += 32) {
        QUAD(b0, 0);  QUAD(b1, 4);  QUAD(b2, 8);  QUAD(b3, 12);
        QUAD(b4, 16); QUAD(b5, 20); QUAD(b6, 24); QUAD(b7, 28);
    }
    // tail t = 1984..1999 (b0..b3 were reloaded with real data at t0=1952)
    TAILQUAD(b0, 1984); TAILQUAD(b1, 1988);
    TAILQUAD(b2, 1992); TAILQUAD(b3, 1996);

#undef TAILQUAD
#undef QUAD
#undef K3STEP
}

extern "C" void kernel_launch(void* const* d_in, const int* in_sizes, int n_in,
                              void* d_out, int out_size, void* d_ws, size_t ws_size,
                              hipStream_t stream)
{
    const float* inp = (const float*)d_in[0];  // [64][4][2000]
    const float* W1  = (const float*)d_in[1];  // [512][4]
    const float* W2  = (const float*)d_in[2];  // [2][512]
    float* out = (float*)d_out;                // [64][2][2000]

    u32* w32    = (u32*)d_ws;
    u16* tail16 = (u16*)((char*)d_ws + TAIL_BYTE_OFF);

    k1_layer1<<<dim3(64), dim3(512), 0, stream>>>(inp, W1, w32, tail16);
    k2_fc2<<<dim3(512), dim3(256), 0, stream>>>(w32, tail16, W2, out);
    k3_layer2<<<dim3(2), dim3(64), 0, stream>>>(out);
}

// Round 5
// 197.563 us; speedup vs baseline: 1.6139x; 1.0847x over previous
//
#include <hip/hip_runtime.h>
#include <cstdint>
#include <cstddef>

// SLAYER SRM-alpha constants, rounded-to-nearest f32 from double
#define THETA_F 10.0f
#define DS_C 0.9048374180359595731642491f   // exp(-0.1)
#define DR_C 0.3678794411714423215955238f   // exp(-1.0)
#define CS_C 0.2718281828459045235360287f   // e/10
#define CR_C -54.3656365691809047072057f    // -2*10*e

typedef unsigned int       u32;
typedef unsigned long long u64;
typedef unsigned short     u16;

// ws layout (exactly 8,192,000 bytes = 64*512*2000 bits):
//   w32 region : u32 [64][62][512]  bits for t in [tb*32, tb*32+32), bit j = t%32
//   tail region: u16 [64][512] at byte offset 64*62*512*4 = 8,126,464, bits t in [1984,2000)
#define W32_WORDS_PER_B  (62 * 512)
#define TAIL_BYTE_OFF    (64 * 62 * 512 * 4)

// ---------------------------------------------------------------------------
// K1: layer-1 fc (K=4, binary inputs -> 16-entry LDS table) + psp_spike.
// One thread per (b,h); 2000 serial steps. 256 blocks x 128 threads:
// 1 block/CU -> 2 waves on 2 SIMDs, 1 wave/SIMD (no issue-port sharing; all
// 256 CUs busy). Per step: 1 prefetched ds_read (8-ahead, double-buffered) +
// ~16 VALU; spike bits accumulate into a u32, coalesced store per 32 steps.
// ---------------------------------------------------------------------------
__global__ __launch_bounds__(128) void k1_layer1(
    const float* __restrict__ inp,                 // [64][4][2000]
    const float* __restrict__ W1,                  // [512][4]
    u32* __restrict__ w32, u16* __restrict__ tail16)
{
    __shared__ float table[16 * 128];
    __shared__ alignas(8) unsigned char codes[2048];

    const int tid = threadIdx.x;                   // 0..127
    const int b   = blockIdx.x >> 2;               // 0..63
    const int h   = ((blockIdx.x & 3) << 7) + tid; // 0..511

    const float w0 = W1[h * 4 + 0];
    const float w1 = W1[h * 4 + 1];
    const float w2 = W1[h * 4 + 2];
    const float w3 = W1[h * 4 + 3];
    // table[c] = ((w0*b0 + w1*b1) + w2*b2) + w3*b3, b_i in {0,1}: bit-identical
    // to the reference einsum contraction (established passing form).
    for (int c = 0; c < 16; ++c) {
        float v = __fmul_rn(w0, (c & 1) ? 1.0f : 0.0f);
        v = __fadd_rn(v, __fmul_rn(w1, (c & 2) ? 1.0f : 0.0f));
        v = __fadd_rn(v, __fmul_rn(w2, (c & 4) ? 1.0f : 0.0f));
        v = __fadd_rn(v, __fmul_rn(w3, (c & 8) ? 1.0f : 0.0f));
        table[c * 128 + tid] = v;
    }
    // stage all 2000 input codes (4-bit per t)
    for (int t = tid; t < 2000; t += 128) {
        const float v0 = inp[(b * 4 + 0) * 2000 + t];
        const float v1 = inp[(b * 4 + 1) * 2000 + t];
        const float v2 = inp[(b * 4 + 2) * 2000 + t];
        const float v3 = inp[(b * 4 + 3) * 2000 + t];
        codes[t] = (unsigned char)((int)(v0 != 0.0f) | ((int)(v1 != 0.0f) << 1) |
                                   ((int)(v2 != 0.0f) << 2) | ((int)(v3 != 0.0f) << 3));
    }
    if (tid < 48) codes[2000 + tid] = 0;   // pad
    __syncthreads();

#define ISSUE(CW, BUF) do {                                                   \
        const u32 lo_ = (u32)(CW), hi_ = (u32)((CW) >> 32);                   \
        BUF[0] = table[((lo_      ) & 15) * 128 + tid];                       \
        BUF[1] = table[((lo_ >>  8) & 15) * 128 + tid];                       \
        BUF[2] = table[((lo_ >> 16) & 15) * 128 + tid];                       \
        BUF[3] = table[((lo_ >> 24) & 15) * 128 + tid];                       \
        BUF[4] = table[((hi_      ) & 15) * 128 + tid];                       \
        BUF[5] = table[((hi_ >>  8) & 15) * 128 + tid];                       \
        BUF[6] = table[((hi_ >> 16) & 15) * 128 + tid];                       \
        BUF[7] = table[((hi_ >> 24) & 15) * 128 + tid];                       \
    } while (0)

    // exact reference rounding (TS=1 mults elided; (u>=theta) == ((u-theta)>=0);
    // xr >= 0 always so cndmask(A+1, A) == A + s bitwise)
#define STEP(AV, BITPOS) do {                                                 \
        const float u_ = __fadd_rn(__fmul_rn(CS_C, ys), __fmul_rn(CR_C, yr)); \
        const bool sp_ = (u_ >= THETA_F);                                     \
        xs = __fadd_rn(__fmul_rn(DS_C, xs), (AV));                            \
        ys = __fmul_rn(DS_C, __fadd_rn(ys, xs));                              \
        const float A_ = __fmul_rn(DR_C, xr);                                 \
        xr = sp_ ? __fadd_rn(A_, 1.0f) : A_;                                  \
        yr = __fmul_rn(DR_C, __fadd_rn(yr, xr));                              \
        bits = sp_ ? (bits | (1u << (BITPOS))) : bits;                        \
    } while (0)

#define STEP8(BUF, J0) do {                                                   \
        _Pragma("unroll")                                                     \
        for (int j_ = 0; j_ < 8; ++j_) STEP(BUF[j_], (J0) + j_);              \
    } while (0)

    float xs = 0.0f, ys = 0.0f, xr = 0.0f, yr = 0.0f;
    u32 bits = 0;
    u32* pw = w32 + (size_t)b * W32_WORDS_PER_B + h;

    float bA[8], bB[8];
    u64 cw = *reinterpret_cast<const u64*>(codes);
    ISSUE(cw, bA);
    u64 c1 = *reinterpret_cast<const u64*>(codes + 8);
    u64 c2 = *reinterpret_cast<const u64*>(codes + 16);
    u64 c3 = *reinterpret_cast<const u64*>(codes + 24);
    u64 c4 = *reinterpret_cast<const u64*>(codes + 32);

    for (int t0 = 0; t0 < 1984; t0 += 32) {
        ISSUE(c1, bB);
        const u64 n1 = *reinterpret_cast<const u64*>(codes + t0 + 40);
        const u64 n2 = *reinterpret_cast<const u64*>(codes + t0 + 48);
        const u64 n3 = *reinterpret_cast<const u64*>(codes + t0 + 56);
        const u64 n4 = *reinterpret_cast<const u64*>(codes + t0 + 64);
        STEP8(bA, 0);
        ISSUE(c2, bA);
        STEP8(bB, 8);
        ISSUE(c3, bB);
        STEP8(bA, 16);
        ISSUE(c4, bA);
        STEP8(bB, 24);
        *pw = bits; pw += 512; bits = 0;
        c1 = n1; c2 = n2; c3 = n3; c4 = n4;
    }
    // tail: bA holds t=1984..1991 (issued with c4 at t0=1952); c1 = codes[1992..2000)
    ISSUE(c1, bB);
    STEP8(bA, 0);
    STEP8(bB, 8);
    tail16[b * 512 + h] = (u16)bits;

#undef STEP8
#undef STEP
#undef ISSUE
}

// ---------------------------------------------------------------------------
// K2: a2[b,o,t] = ascending-h sum of W2[o,h]*s1[b,h,t]; cndmask +0.0 adds are
// bit-identical to the reference skip-zero ascending sum.
// Block per (b, it): stages 8 tb-words x 512 h in LDS, thread per t.
// ---------------------------------------------------------------------------
__global__ __launch_bounds__(256) void k2_fc2(
    const u32* __restrict__ w32, const u16* __restrict__ tail16,
    const float* __restrict__ W2,                  // [2][512]
    float* __restrict__ a2)                        // [128][2000]
{
    __shared__ float w2s[1024];
    __shared__ u32 stage[4096];                    // [local tb 0..7][h 0..511]

    const int tid = threadIdx.x;
    const int b  = blockIdx.x >> 3;
    const int it = blockIdx.x & 7;

    for (int j = tid; j < 1024; j += 256) w2s[j] = W2[j];
    #pragma unroll
    for (int k = 0; k < 16; ++k) {
        const int l = tid + (k << 8);              // 0..4095
        const int gtb = (it << 3) + (l >> 9);
        u32 v = 0;
        if (gtb < 62)       v = w32[((size_t)b * 62 + gtb) * 512 + (l & 511)];
        else if (gtb == 62) v = (u32)tail16[b * 512 + (l & 511)];
        stage[l] = v;
    }
    __syncthreads();

    const int t = (it << 8) + tid;
    if (t < 2000) {
        const u32* srow = stage + ((tid >> 5) << 9);
        const int sh = tid & 31;
        float acc0 = 0.0f, acc1 = 0.0f;
        #pragma unroll 8
        for (int hh = 0; hh < 512; ++hh) {
            const bool on = (srow[hh] >> sh) & 1u;
            acc0 = __fadd_rn(acc0, on ? w2s[hh] : 0.0f);
            acc1 = __fadd_rn(acc1, on ? w2s[512 + hh] : 0.0f);
        }
        a2[(size_t)(b * 2 + 0) * 2000 + t] = acc0;
        a2[(size_t)(b * 2 + 1) * 2000 + t] = acc1;
    }
}

// ---------------------------------------------------------------------------
// K3: layer-2 psp_spike + final psp readout, fused. 128 chains (b,o).
// Restrict-pair pointers (called with in==out): reads rin[t+32..], writes
// rout[t..] — disjoint at any instant; the iter-(k+1) store to an address
// loaded at iter k is ordered by DATA dependence (stored p depends on the
// loaded a), so deleting the compiler's WAR vmcnt-drain is hardware-safe.
// Full 32-step unroll, 8 named float4 buffers. grid 2 x block 64.
// ---------------------------------------------------------------------------
__global__ __launch_bounds__(64) void k3_layer2(
    const float* __restrict__ rin, float* __restrict__ rout)
{
    const int idx = blockIdx.x * 64 + threadIdx.x; // row = b*2+o, 0..127
    const float* rowi = rin  + (size_t)idx * 2000;
    float*       rowo = rout + (size_t)idx * 2000;

    float xs2 = 0.0f, ys2 = 0.0f, xr2 = 0.0f, yr2 = 0.0f;
    float xs3 = 0.0f, ys3 = 0.0f;

    // exact reference rounding; xs3,xr2 >= 0 so cndmask(B+1,B) == B+s bitwise
#define K3STEP(AV, POUT) do {                                                 \
        const float u_ = __fadd_rn(__fmul_rn(CS_C, ys2), __fmul_rn(CR_C, yr2)); \
        const bool sp_ = (u_ >= THETA_F);                                     \
        POUT = __fmul_rn(CS_C, ys3);      /* readout BEFORE consuming s2[t] */\
        xs2 = __fadd_rn(__fmul_rn(DS_C, xs2), (AV));                          \
        ys2 = __fmul_rn(DS_C, __fadd_rn(ys2, xs2));                           \
        const float A_ = __fmul_rn(DR_C, xr2);                                \
        xr2 = sp_ ? __fadd_rn(A_, 1.0f) : A_;                                 \
        yr2 = __fmul_rn(DR_C, __fadd_rn(yr2, xr2));                           \
        const float B_ = __fmul_rn(DS_C, xs3);                                \
        xs3 = sp_ ? __fadd_rn(B_, 1.0f) : B_;                                 \
        ys3 = __fmul_rn(DS_C, __fadd_rn(ys3, xs3));                           \
    } while (0)

    // consume BK (4 steps at t0+OFF), store p-quad, reload BK from t0+32+OFF
#define QUAD(BK, OFF) do {                                                    \
        float p0_, p1_, p2_, p3_;                                             \
        K3STEP(BK.x, p0_); K3STEP(BK.y, p1_);                                 \
        K3STEP(BK.z, p2_); K3STEP(BK.w, p3_);                                 \
        *reinterpret_cast<float4*>(rowo + t0 + (OFF)) =                       \
            make_float4(p0_, p1_, p2_, p3_);                                  \
        const int tn_ = t0 + 32 + (OFF);                                      \
        BK = *reinterpret_cast<const float4*>(rowi + ((tn_ < 2000) ? tn_ : 1984)); \
    } while (0)

#define TAILQUAD(BK, TPOS) do {                                               \
        float p0_, p1_, p2_, p3_;                                             \
        K3STEP(BK.x, p0_); K3STEP(BK.y, p1_);                                 \
        K3STEP(BK.z, p2_); K3STEP(BK.w, p3_);                                 \
        *reinterpret_cast<float4*>(rowo + (TPOS)) =                           \
            make_float4(p0_, p1_, p2_, p3_);                                  \
    } while (0)

    float4 b0 = *reinterpret_cast<const float4*>(rowi + 0);
    float4 b1 = *reinterpret_cast<const float4*>(rowi + 4);
    float4 b2 = *reinterpret_cast<const float4*>(rowi + 8);
    float4 b3 = *reinterpret_cast<const float4*>(rowi + 12);
    float4 b4 = *reinterpret_cast<const float4*>(rowi + 16);
    float4 b5 = *reinterpret_cast<const float4*>(rowi + 20);
    float4 b6 = *reinterpret_cast<const float4*>(rowi + 24);
    float4 b7 = *reinterpret_cast<const float4*>(rowi + 28);

    for (int t0 = 0; t0 < 1984; t0 += 32) {
        QUAD(b0, 0);  QUAD(b1, 4);  QUAD(b2, 8);  QUAD(b3, 12);
        QUAD(b4, 16); QUAD(b5, 20); QUAD(b6, 24); QUAD(b7, 28);
    }
    // tail t = 1984..1999 (b0..b3 were reloaded with real data at t0=1952)
    TAILQUAD(b0, 1984); TAILQUAD(b1, 1988);
    TAILQUAD(b2, 1992); TAILQUAD(b3, 1996);

#undef TAILQUAD
#undef QUAD
#undef K3STEP
}

extern "C" void kernel_launch(void* const* d_in, const int* in_sizes, int n_in,
                              void* d_out, int out_size, void* d_ws, size_t ws_size,
                              hipStream_t stream)
{
    const float* inp = (const float*)d_in[0];  // [64][4][2000]
    const float* W1  = (const float*)d_in[1];  // [512][4]
    const float* W2  = (const float*)d_in[2];  // [2][512]
    float* out = (float*)d_out;                // [64][2][2000]

    u32* w32    = (u32*)d_ws;
    u16* tail16 = (u16*)((char*)d_ws + TAIL_BYTE_OFF);

    k1_layer1<<<dim3(256), dim3(128), 0, stream>>>(inp, W1, w32, tail16);
    k2_fc2<<<dim3(512), dim3(256), 0, stream>>>(w32, tail16, W2, out);
    k3_layer2<<<dim3(2), dim3(64), 0, stream>>>(out, out);
}